// Round 6
// baseline (257.677 us; speedup 1.0000x reference)
//
#include <hip/hip_runtime.h>

#define NB 8192
#define NL 64
#define NH 128

typedef __bf16 bf16x8 __attribute__((ext_vector_type(8)));
typedef float f32x4 __attribute__((ext_vector_type(4)));
typedef unsigned short ushort8 __attribute__((ext_vector_type(8)));

// phys->logical permutation for the h buffer (GEMM1 writeback pair-packing):
// phys p = w*32 + ci*2 + half  holds logical  w*32 + half*16 + ci
__device__ __host__ __forceinline__ int p2l(int p) {
  return (p & ~31) + ((p & 1) << 4) + ((p & 31) >> 1);
}
// phys->logical permutation for the x=concat(x1,x2) buffer (x1x2 pair-packing):
// phys even p -> x1 col p/2 ; phys odd p -> x2 col p/2 (logical 64+p/2)
__device__ __host__ __forceinline__ int pi2(int p) {
  return (p & 1) ? 64 + (p >> 1) : (p >> 1);
}

__device__ __forceinline__ unsigned pk2(float lo, float hi) {
  union { __bf16 b[2]; unsigned u; } t;
  t.b[0] = (__bf16)lo; t.b[1] = (__bf16)hi;
  return t.u;
}

// ---------------------------------------------------------------------------
// Repack weights (f32 -> bf16 MFMA-B fragments) + permuted bf16 gamma/beta.
// wp1: [layer3][ntile8][kstep4][lane64][reg8]; value = W1[l][srck][n]
//      srck = k (layer 0) | pi2(k) (layers 1,2)   [x-buffer phys layout]
// wp2: [layer3][ntile4][kstep4][lane64][reg8]; value = W2[l][p2l(k)][n]
// gbt: bf16 [layer3][2][128]; gbt[l][g][p] = param[l][p2l(p)]
// ---------------------------------------------------------------------------
__global__ __launch_bounds__(256) void repack_w(const float* __restrict__ W1,
                                                const float* __restrict__ W2,
                                                const float* __restrict__ gamma,
                                                const float* __restrict__ beta,
                                                unsigned short* __restrict__ wp1,
                                                unsigned short* __restrict__ wp2,
                                                unsigned short* __restrict__ gbt) {
  int t = blockIdx.x * 256 + threadIdx.x;
  int lane = t & 63, g = t >> 6;
  if (g < 96) {                                   // W1: 3*8*4 groups
    int layer = g >> 5, rem = g & 31, nt = rem >> 2, ks = rem & 3;
    int n = nt * 16 + (lane & 15);
    int kb = ks * 32 + (lane >> 4) * 8;
    ushort8 v;
#pragma unroll
    for (int r = 0; r < 8; ++r) {
      int k = kb + r;
      int srck = (layer == 0) ? k : pi2(k);
      union { __bf16 b; unsigned short u; } c;
      c.b = (__bf16)W1[(layer * 128 + srck) * 128 + n];
      v[r] = c.u;
    }
    *reinterpret_cast<ushort8*>(wp1 + ((size_t)g * 64 + lane) * 8) = v;
  } else if (g < 144) {                           // W2: 3*4*4 groups, k by p2l
    int g2 = g - 96;
    int layer = g2 >> 4, rem = g2 & 15, nt = rem >> 2, ks = rem & 3;
    int n = nt * 16 + (lane & 15);
    int kb = ks * 32 + (lane >> 4) * 8;
    ushort8 v;
#pragma unroll
    for (int r = 0; r < 8; ++r) {
      union { __bf16 b; unsigned short u; } c;
      c.b = (__bf16)W2[(layer * 128 + p2l(kb + r)) * 64 + n];
      v[r] = c.u;
    }
    *reinterpret_cast<ushort8*>(wp2 + ((size_t)g2 * 64 + lane) * 8) = v;
  } else if (g < 150) {                           // gamma/beta bf16, p2l order
    int g2 = g - 144;                             // 0..5
    int layer = g2 >> 1, param = g2 & 1;
    const float* src = (param == 0 ? gamma : beta) + layer * 128;
    unsigned short* dst = gbt + (layer * 2 + param) * 128;
    int p0 = lane * 2;
#pragma unroll
    for (int u = 0; u < 2; ++u) {
      union { __bf16 b; unsigned short x; } c;
      c.b = (__bf16)src[p2l(p0 + u)];
      dst[p0 + u] = c.x;
    }
  }
}

// ---------------------------------------------------------------------------
// Fused depth-3 MLP stack, one workgroup (4 waves) per batch row b.
// Single in-place activation buffer xbuf: bf16 [64][128], XOR-swizzled
// (byte ^= (row&7)<<4). LDS 17.9 KB -> 8 blocks/CU.
// GEMM1 is split into two mt-halves (rows 0-31 then 32-63) so peak live
// accumulators drop 32->16 regs; with arch+acc unified on gfx950 this brings
// total demand under 64 => __launch_bounds__(256,8) reaches 8 waves/SIMD
// WITHOUT the R4 spill (R4's demand was ~108; verify via FETCH_SIZE ~132MB).
// ---------------------------------------------------------------------------
__global__ __launch_bounds__(256, 8) void fused_mlp(
    const float* __restrict__ hidden,
    const float* __restrict__ b1,
    const float* __restrict__ b2,
    const unsigned short* __restrict__ wp1u,
    const unsigned short* __restrict__ wp2u,
    const unsigned short* __restrict__ gbt,
    float* __restrict__ out) {
  __shared__ __align__(16) unsigned short xbuf[NL * NH];   // 16384 B
  __shared__ __align__(16) unsigned short gbuf[768];       // 1536 B

  const int tid = threadIdx.x;
  const int wave = tid >> 6, lane = tid & 63;
  const int ci = lane & 15, lg = lane >> 4;
  char* xc = reinterpret_cast<char*>(xbuf);
  char* gc = reinterpret_cast<char*>(gbuf);

  // thread-invariant address pieces for fragment reads
  const int abase = ci * 256;                 // row (=..+ci) byte base (mod tiles)
  const int axor = (ci & 7) << 4;             // row-swizzle for rows ≡ ci (mod 8)

  // stage gamma/beta (bf16) into LDS
  {
    const unsigned* s = reinterpret_cast<const unsigned*>(gbt);
    unsigned* d = reinterpret_cast<unsigned*>(gbuf);
    if (tid < 128) { d[tid] = s[tid]; d[tid + 128] = s[tid + 128]; d[tid + 256] = s[tid + 256]; }
  }

  // ---- stage 0: load hidden[b] (f32) -> xbuf (bf16, swizzled, identity) ----
  const float* src = hidden + (size_t)blockIdx.x * (NL * NH);
#pragma unroll
  for (int i = 0; i < 4; ++i) {
    int f = i * 256 + tid;          // 8-elem chunk id, 0..1023
    int row = f >> 4;
    int cb = (f & 15) * 16;         // byte column
    const float4* p = reinterpret_cast<const float4*>(src + f * 8);
    float4 a = p[0], bq = p[1];
    bf16x8 v;
    v[0] = (__bf16)a.x;  v[1] = (__bf16)a.y;  v[2] = (__bf16)a.z;  v[3] = (__bf16)a.w;
    v[4] = (__bf16)bq.x; v[5] = (__bf16)bq.y; v[6] = (__bf16)bq.z; v[7] = (__bf16)bq.w;
    *reinterpret_cast<bf16x8*>(xc + row * 256 + (cb ^ ((row & 7) << 4))) = v;
  }
  __syncthreads();

  for (int layer = 0; layer < 3; ++layer) {
    const unsigned short* wl1 = wp1u + (size_t)layer * 16384;
    const float bv0 = b1[layer * 128 + wave * 32 + ci];
    const float bv1 = b1[layer * 128 + wave * 32 + 16 + ci];
    const int dby = (wave * 16 + ci) * 4;

    // ========== GEMM1: h = x @ W1 + b1, two mt-halves (16 acc regs live) ====
#pragma unroll 1
    for (int half = 0; half < 2; ++half) {
      f32x4 acc[2][2];
#pragma unroll
      for (int m2 = 0; m2 < 2; ++m2) {
        acc[m2][0] = f32x4{0.f, 0.f, 0.f, 0.f};
        acc[m2][1] = f32x4{0.f, 0.f, 0.f, 0.f};
      }
#pragma unroll
      for (int ks = 0; ks < 4; ++ks) {
        bf16x8 bf0 = *reinterpret_cast<const bf16x8*>(
            wl1 + (((wave * 2 + 0) * 4 + ks) * 64 + lane) * 8);
        bf16x8 bf1 = *reinterpret_cast<const bf16x8*>(
            wl1 + (((wave * 2 + 1) * 4 + ks) * 64 + lane) * 8);
        int cbx = ((ks * 64 + lg * 16) ^ axor) + abase;
#pragma unroll
        for (int m2 = 0; m2 < 2; ++m2) {
          bf16x8 af = *reinterpret_cast<const bf16x8*>(
              xc + (half * 2 + m2) * 4096 + cbx);
          acc[m2][0] = __builtin_amdgcn_mfma_f32_16x16x32_bf16(af, bf0, acc[m2][0], 0, 0, 0);
          acc[m2][1] = __builtin_amdgcn_mfma_f32_16x16x32_bf16(af, bf1, acc[m2][1], 0, 0, 0);
        }
      }
      // B1a/B1b: all waves done reading this half's rows before overwriting them
      __syncthreads();
      // writeback h rows [half*32, half*32+32): pair-pack (c, c+16) -> phys dword
#pragma unroll
      for (int m2 = 0; m2 < 2; ++m2)
#pragma unroll
        for (int r = 0; r < 4; ++r) {
          int row = (half * 2 + m2) * 16 + lg * 4 + r;
          *reinterpret_cast<unsigned*>(
              xc + row * 256 + (dby ^ ((row & 7) << 4))) =
              pk2(acc[m2][0][r] + bv0, acc[m2][1][r] + bv1);
        }
    }
    __syncthreads();  // B2: h visible to all

    // ========== LayerNorm + ReLU in place: 4 threads per row ================
    {
      const int row = wave * 16 + (lane >> 2);
      const int q = lane & 3;
      const int rb = row * 256, rx = (row & 7) << 4;
      bf16x8 h0 = *reinterpret_cast<const bf16x8*>(xc + rb + ((q * 64 + 0) ^ rx));
      bf16x8 h1 = *reinterpret_cast<const bf16x8*>(xc + rb + ((q * 64 + 16) ^ rx));
      bf16x8 h2 = *reinterpret_cast<const bf16x8*>(xc + rb + ((q * 64 + 32) ^ rx));
      bf16x8 h3 = *reinterpret_cast<const bf16x8*>(xc + rb + ((q * 64 + 48) ^ rx));
      float s = 0.f, sq = 0.f;
#pragma unroll
      for (int j = 0; j < 8; ++j) {
        float v0 = (float)h0[j], v1 = (float)h1[j], v2 = (float)h2[j], v3 = (float)h3[j];
        s += (v0 + v1) + (v2 + v3);
        sq = fmaf(v0, v0, fmaf(v1, v1, fmaf(v2, v2, fmaf(v3, v3, sq))));
      }
      s += __shfl_xor(s, 1);  sq += __shfl_xor(sq, 1);
      s += __shfl_xor(s, 2);  sq += __shfl_xor(sq, 2);
      float mu = s * (1.f / 128.f);
      float var = sq * (1.f / 128.f) - mu * mu;
      float rs = rsqrtf(var + 1e-5f);
      const char* gl = gc + layer * 512 + q * 64;
#pragma unroll
      for (int cch = 0; cch < 4; ++cch) {
        bf16x8 hv = (cch == 0) ? h0 : (cch == 1) ? h1 : (cch == 2) ? h2 : h3;
        bf16x8 gv = *reinterpret_cast<const bf16x8*>(gl + cch * 16);
        bf16x8 bv = *reinterpret_cast<const bf16x8*>(gl + 256 + cch * 16);
        bf16x8 y;
#pragma unroll
        for (int j = 0; j < 8; ++j) {
          float a = rs * (float)gv[j];
          float c = fmaf(-mu, a, (float)bv[j]);
          y[j] = (__bf16)fmaxf(fmaf((float)hv[j], a, c), 0.f);
        }
        *reinterpret_cast<bf16x8*>(xc + rb + ((q * 64 + cch * 16) ^ rx)) = y;
      }
    }
    __syncthreads();  // B3: normalized x visible

    // ========== GEMM2: x1 = xn @ W2 + b2 (wave -> cols [wave*16,+16)) =======
    f32x4 acc2[4];
#pragma unroll
    for (int mt = 0; mt < 4; ++mt) acc2[mt] = f32x4{0.f, 0.f, 0.f, 0.f};
    const unsigned short* wl2 = wp2u + (size_t)layer * 8192;
#pragma unroll
    for (int ks = 0; ks < 4; ++ks) {
      bf16x8 bfr = *reinterpret_cast<const bf16x8*>(
          wl2 + ((wave * 4 + ks) * 64 + lane) * 8);
      int cbx = ((ks * 64 + lg * 16) ^ axor) + abase;
#pragma unroll
      for (int mt = 0; mt < 4; ++mt) {
        bf16x8 af = *reinterpret_cast<const bf16x8*>(xc + mt * 4096 + cbx);
        acc2[mt] = __builtin_amdgcn_mfma_f32_16x16x32_bf16(af, bfr, acc2[mt], 0, 0, 0);
      }
    }
    float b2v = b2[layer * 64 + wave * 16 + ci];

    // column max over all 64 rows: in-reg + 2 shuffles (lane holds col wave*16+ci)
    float mm;
    {
      float m = -3.0e38f;
#pragma unroll
      for (int mt = 0; mt < 4; ++mt)
#pragma unroll
        for (int r = 0; r < 4; ++r) m = fmaxf(m, acc2[mt][r]);
      m = fmaxf(m, __shfl_xor(m, 16));
      m = fmaxf(m, __shfl_xor(m, 32));
      mm = m + b2v;
    }

    if (layer < 2) {
      __syncthreads();  // B4: all xn reads done before x1x2 overwrites xbuf
      // pack (x1[row][c], x2[c]) -> phys dword d = wave*16+ci
#pragma unroll
      for (int mt = 0; mt < 4; ++mt)
#pragma unroll
        for (int r = 0; r < 4; ++r) {
          int row = mt * 16 + lg * 4 + r;
          *reinterpret_cast<unsigned*>(
              xc + row * 256 + (dby ^ ((row & 7) << 4))) =
              pk2(acc2[mt][r] + b2v, mm);
        }
      __syncthreads();  // B5: new x visible for next layer
    } else {
      // final output (f32): out[b] = [x2_3, x2_3]
      if (lg == 0) {
        size_t o = (size_t)blockIdx.x * 128 + wave * 16 + ci;
        out[o] = mm;
        out[o + 64] = mm;
      }
    }
  }
}

extern "C" void kernel_launch(void* const* d_in, const int* in_sizes, int n_in,
                              void* d_out, int out_size, void* d_ws, size_t ws_size,
                              hipStream_t stream) {
  const float* hidden = (const float*)d_in[0];
  const float* W1 = (const float*)d_in[1];
  const float* b1 = (const float*)d_in[2];
  const float* gamma = (const float*)d_in[3];
  const float* beta = (const float*)d_in[4];
  const float* W2 = (const float*)d_in[5];
  const float* b2 = (const float*)d_in[6];
  (void)in_sizes; (void)n_in; (void)out_size; (void)ws_size;

  unsigned short* wp1 = (unsigned short*)d_ws;          // 49152 ushorts
  unsigned short* wp2 = wp1 + 3 * 8 * 4 * 64 * 8;       // 24576 ushorts
  unsigned short* gbt = wp2 + 3 * 4 * 4 * 64 * 8;       // 768 ushorts (bf16)
  float* out = (float*)d_out;

  repack_w<<<38, 256, 0, stream>>>(W1, W2, gamma, beta, wp1, wp2, gbt);
  fused_mlp<<<NB, 256, 0, stream>>>(hidden, b1, b2, wp1, wp2, gbt, out);
}

// Round 7
// 144.192 us; speedup vs baseline: 1.7870x; 1.7870x over previous
//
#include <hip/hip_runtime.h>

#define NB 8192
#define NL 64
#define NH 128

typedef __bf16 bf16x8 __attribute__((ext_vector_type(8)));
typedef float f32x4 __attribute__((ext_vector_type(4)));
typedef float f32x2 __attribute__((ext_vector_type(2)));
typedef unsigned short ushort8 __attribute__((ext_vector_type(8)));

// phys->logical permutation for the h buffer (GEMM1 writeback pair-packing):
// phys p = w*32 + ci*2 + half  holds logical  w*32 + half*16 + ci
__device__ __host__ __forceinline__ int p2l(int p) {
  return (p & ~31) + ((p & 1) << 4) + ((p & 31) >> 1);
}
// phys->logical permutation for the x=concat(x1,x2) buffer (x1x2 pair-packing):
// phys even p -> x1 col p/2 ; phys odd p -> x2 col p/2 (logical 64+p/2)
__device__ __host__ __forceinline__ int pi2(int p) {
  return (p & 1) ? 64 + (p >> 1) : (p >> 1);
}

__device__ __forceinline__ unsigned pk2(float lo, float hi) {
  union { __bf16 b[2]; unsigned u; } t;
  t.b[0] = (__bf16)lo; t.b[1] = (__bf16)hi;
  return t.u;
}

// ---------------------------------------------------------------------------
// Repack weights (f32 -> bf16 MFMA-B fragments) + permuted f32 gamma/beta.
// wp1: [layer3][ntile8][kstep4][lane64][reg8]; value = W1[l][srck][n]
//      srck = k (layer 0) | pi2(k) (layers 1,2)   [x-buffer phys layout]
// wp2: [layer3][ntile4][kstep4][lane64][reg8]; value = W2[l][p2l(k)][n]
// gbt: f32 [layer3][2][4(q)][36]; gbt[l][g][q][k] = param[l][p2l(q*32+k)]
//      (q-stride 36 floats = 144B so the 4 q-broadcast reads hit distinct banks)
// ---------------------------------------------------------------------------
__global__ __launch_bounds__(256) void repack_w(const float* __restrict__ W1,
                                                const float* __restrict__ W2,
                                                const float* __restrict__ gamma,
                                                const float* __restrict__ beta,
                                                unsigned short* __restrict__ wp1,
                                                unsigned short* __restrict__ wp2,
                                                float* __restrict__ gbt) {
  int t = blockIdx.x * 256 + threadIdx.x;
  int lane = t & 63, g = t >> 6;
  if (g < 96) {                                   // W1: 3*8*4 groups
    int layer = g >> 5, rem = g & 31, nt = rem >> 2, ks = rem & 3;
    int n = nt * 16 + (lane & 15);
    int kb = ks * 32 + (lane >> 4) * 8;
    ushort8 v;
#pragma unroll
    for (int r = 0; r < 8; ++r) {
      int k = kb + r;
      int srck = (layer == 0) ? k : pi2(k);
      union { __bf16 b; unsigned short u; } c;
      c.b = (__bf16)W1[(layer * 128 + srck) * 128 + n];
      v[r] = c.u;
    }
    *reinterpret_cast<ushort8*>(wp1 + ((size_t)g * 64 + lane) * 8) = v;
  } else if (g < 144) {                           // W2: 3*4*4 groups, k by p2l
    int g2 = g - 96;
    int layer = g2 >> 4, rem = g2 & 15, nt = rem >> 2, ks = rem & 3;
    int n = nt * 16 + (lane & 15);
    int kb = ks * 32 + (lane >> 4) * 8;
    ushort8 v;
#pragma unroll
    for (int r = 0; r < 8; ++r) {
      union { __bf16 b; unsigned short u; } c;
      c.b = (__bf16)W2[(layer * 128 + p2l(kb + r)) * 64 + n];
      v[r] = c.u;
    }
    *reinterpret_cast<ushort8*>(wp2 + ((size_t)g2 * 64 + lane) * 8) = v;
  } else if (g < 150) {                           // gamma/beta f32, padded
    int g2 = g - 144;                             // 0..5
    int layer = g2 >> 1, param = g2 & 1;
    const float* src = (param == 0 ? gamma : beta) + layer * 128;
    float* dst = gbt + layer * 288 + param * 144;
    int p0 = lane * 2;
#pragma unroll
    for (int u = 0; u < 2; ++u) {
      int p = p0 + u;
      dst[(p >> 5) * 36 + (p & 31)] = src[p2l(p)];
    }
  }
}

// ---------------------------------------------------------------------------
// Fused depth-3 MLP stack, one workgroup (4 waves) per batch row b.
// Single in-place activation buffer xbuf: bf16 [64][128], XOR-swizzled
// (byte ^= (row&7)<<4). R5 structure; VALU cuts: f32 gamma/beta (no cvts),
// bias folded into MFMA C-init, packed-f32 LayerNorm math (v_pk_*_f32).
// NOTE: no min-waves bound — R4/R6 proved forcing 8 waves/EU spills (~100KB/
// block scratch). Natural allocation runs 4 waves/SIMD, register-pinned.
// ---------------------------------------------------------------------------
__global__ __launch_bounds__(256) void fused_mlp(
    const float* __restrict__ hidden,
    const float* __restrict__ b1,
    const float* __restrict__ b2,
    const unsigned short* __restrict__ wp1u,
    const unsigned short* __restrict__ wp2u,
    const float* __restrict__ gbt,
    float* __restrict__ out) {
  __shared__ __align__(16) unsigned short xbuf[NL * NH];   // 16384 B
  __shared__ __align__(16) float gbuf[864];                // 3456 B

  const int tid = threadIdx.x;
  const int wave = tid >> 6, lane = tid & 63;
  const int ci = lane & 15, lg = lane >> 4;
  char* xc = reinterpret_cast<char*>(xbuf);

  // thread-invariant address pieces for fragment reads
  const int abase = ci * 256;                 // row (=..+ci) byte base (mod tiles)
  const int axor = (ci & 7) << 4;             // row-swizzle for rows ≡ ci (mod 8)

  // stage gamma/beta (f32, padded layout) into LDS
  {
    if (tid < 96) {
      // 864 floats: threads 0..95 copy 9 each
#pragma unroll
      for (int u = 0; u < 9; ++u) gbuf[tid * 9 + u] = gbt[tid * 9 + u];
    }
  }

  // ---- stage 0: load hidden[b] (f32) -> xbuf (bf16, swizzled, identity) ----
  const float* src = hidden + (size_t)blockIdx.x * (NL * NH);
#pragma unroll
  for (int i = 0; i < 4; ++i) {
    int f = i * 256 + tid;          // 8-elem chunk id, 0..1023
    int row = f >> 4;
    int cb = (f & 15) * 16;         // byte column
    const float4* p = reinterpret_cast<const float4*>(src + f * 8);
    float4 a = p[0], bq = p[1];
    bf16x8 v;
    v[0] = (__bf16)a.x;  v[1] = (__bf16)a.y;  v[2] = (__bf16)a.z;  v[3] = (__bf16)a.w;
    v[4] = (__bf16)bq.x; v[5] = (__bf16)bq.y; v[6] = (__bf16)bq.z; v[7] = (__bf16)bq.w;
    *reinterpret_cast<bf16x8*>(xc + row * 256 + (cb ^ ((row & 7) << 4))) = v;
  }
  __syncthreads();

  for (int layer = 0; layer < 3; ++layer) {
    const unsigned short* wl1 = wp1u + (size_t)layer * 16384;
    const float bv0 = b1[layer * 128 + wave * 32 + ci];
    const float bv1 = b1[layer * 128 + wave * 32 + 16 + ci];
    const int dby = (wave * 16 + ci) * 4;

    // ========== GEMM1: h = x @ W1 + b1 (bias in C-init; wave -> 32 cols) ====
    f32x4 acc[4][2];
#pragma unroll
    for (int mt = 0; mt < 4; ++mt) {
      acc[mt][0] = f32x4{bv0, bv0, bv0, bv0};
      acc[mt][1] = f32x4{bv1, bv1, bv1, bv1};
    }
#pragma unroll
    for (int ks = 0; ks < 4; ++ks) {
      bf16x8 bf0 = *reinterpret_cast<const bf16x8*>(
          wl1 + (((wave * 2 + 0) * 4 + ks) * 64 + lane) * 8);
      bf16x8 bf1 = *reinterpret_cast<const bf16x8*>(
          wl1 + (((wave * 2 + 1) * 4 + ks) * 64 + lane) * 8);
      int cbx = ((ks * 64 + lg * 16) ^ axor) + abase;
#pragma unroll
      for (int mt = 0; mt < 4; ++mt) {
        bf16x8 af = *reinterpret_cast<const bf16x8*>(xc + mt * 4096 + cbx);
        acc[mt][0] = __builtin_amdgcn_mfma_f32_16x16x32_bf16(af, bf0, acc[mt][0], 0, 0, 0);
        acc[mt][1] = __builtin_amdgcn_mfma_f32_16x16x32_bf16(af, bf1, acc[mt][1], 0, 0, 0);
      }
    }
    __syncthreads();  // B1: all x reads done before h overwrites xbuf

    // writeback h: pair-pack logical (c, c+16) -> phys dword d = wave*16+ci
#pragma unroll
    for (int mt = 0; mt < 4; ++mt)
#pragma unroll
      for (int r = 0; r < 4; ++r) {
        int row = mt * 16 + lg * 4 + r;
        *reinterpret_cast<unsigned*>(
            xc + row * 256 + (dby ^ ((row & 7) << 4))) =
            pk2(acc[mt][0][r], acc[mt][1][r]);
      }
    __syncthreads();  // B2: h visible to all

    // ========== LayerNorm + ReLU in place: 4 threads per row, pk-f32 ========
    {
      const int row = wave * 16 + (lane >> 2);
      const int q = lane & 3;
      const int rb = row * 256, rx = (row & 7) << 4;
      bf16x8 h0 = *reinterpret_cast<const bf16x8*>(xc + rb + ((q * 64 + 0) ^ rx));
      bf16x8 h1 = *reinterpret_cast<const bf16x8*>(xc + rb + ((q * 64 + 16) ^ rx));
      bf16x8 h2 = *reinterpret_cast<const bf16x8*>(xc + rb + ((q * 64 + 32) ^ rx));
      bf16x8 h3 = *reinterpret_cast<const bf16x8*>(xc + rb + ((q * 64 + 48) ^ rx));
      f32x2 f[16];
#pragma unroll
      for (int cch = 0; cch < 4; ++cch) {
        bf16x8 hv = (cch == 0) ? h0 : (cch == 1) ? h1 : (cch == 2) ? h2 : h3;
#pragma unroll
        for (int j2 = 0; j2 < 4; ++j2)
          f[cch * 4 + j2] = f32x2{(float)hv[j2 * 2], (float)hv[j2 * 2 + 1]};
      }
      f32x2 s2 = {0.f, 0.f}, q2 = {0.f, 0.f};
#pragma unroll
      for (int i = 0; i < 16; ++i) { s2 += f[i]; q2 += f[i] * f[i]; }
      float s = s2.x + s2.y, sq = q2.x + q2.y;
      s += __shfl_xor(s, 1);  sq += __shfl_xor(sq, 1);
      s += __shfl_xor(s, 2);  sq += __shfl_xor(sq, 2);
      float mu = s * (1.f / 128.f);
      float var = sq * (1.f / 128.f) - mu * mu;
      float rs = rsqrtf(var + 1e-5f);
      const f32x2* gl = reinterpret_cast<const f32x2*>(gbuf + layer * 288 + q * 36);
      const f32x2* bl = reinterpret_cast<const f32x2*>(gbuf + layer * 288 + 144 + q * 36);
#pragma unroll
      for (int cch = 0; cch < 4; ++cch) {
        union { unsigned u[4]; bf16x8 v; } yy;
#pragma unroll
        for (int j2 = 0; j2 < 4; ++j2) {
          int i = cch * 4 + j2;
          f32x2 a2 = gl[i] * rs;
          f32x2 c2 = bl[i] - a2 * mu;
          f32x2 y2 = f[i] * a2 + c2;
          yy.u[j2] = pk2(fmaxf(y2.x, 0.f), fmaxf(y2.y, 0.f));
        }
        *reinterpret_cast<bf16x8*>(xc + rb + ((q * 64 + cch * 16) ^ rx)) = yy.v;
      }
    }
    __syncthreads();  // B3: normalized x visible

    // ========== GEMM2: x1 = xn @ W2 + b2 (bias in C-init; wave -> 16 cols) ==
    f32x4 acc2[4];
    {
      float b2v = b2[layer * 64 + wave * 16 + ci];
#pragma unroll
      for (int mt = 0; mt < 4; ++mt) acc2[mt] = f32x4{b2v, b2v, b2v, b2v};
    }
    const unsigned short* wl2 = wp2u + (size_t)layer * 8192;
#pragma unroll
    for (int ks = 0; ks < 4; ++ks) {
      bf16x8 bfr = *reinterpret_cast<const bf16x8*>(
          wl2 + ((wave * 4 + ks) * 64 + lane) * 8);
      int cbx = ((ks * 64 + lg * 16) ^ axor) + abase;
#pragma unroll
      for (int mt = 0; mt < 4; ++mt) {
        bf16x8 af = *reinterpret_cast<const bf16x8*>(xc + mt * 4096 + cbx);
        acc2[mt] = __builtin_amdgcn_mfma_f32_16x16x32_bf16(af, bfr, acc2[mt], 0, 0, 0);
      }
    }

    // column max over all 64 rows: in-reg + 2 shuffles (lane holds col wave*16+ci)
    float mm;
    {
      float m = -3.0e38f;
#pragma unroll
      for (int mt = 0; mt < 4; ++mt)
#pragma unroll
        for (int r = 0; r < 4; ++r) m = fmaxf(m, acc2[mt][r]);
      m = fmaxf(m, __shfl_xor(m, 16));
      m = fmaxf(m, __shfl_xor(m, 32));
      mm = m;
    }

    if (layer < 2) {
      __syncthreads();  // B4: all xn reads done before x1x2 overwrites xbuf
      // pack (x1[row][c], x2[c]) -> phys dword d = wave*16+ci
#pragma unroll
      for (int mt = 0; mt < 4; ++mt)
#pragma unroll
        for (int r = 0; r < 4; ++r) {
          int row = mt * 16 + lg * 4 + r;
          *reinterpret_cast<unsigned*>(
              xc + row * 256 + (dby ^ ((row & 7) << 4))) =
              pk2(acc2[mt][r], mm);
        }
      __syncthreads();  // B5: new x visible for next layer
    } else {
      // final output (f32): out[b] = [x2_3, x2_3]
      if (lg == 0) {
        size_t o = (size_t)blockIdx.x * 128 + wave * 16 + ci;
        out[o] = mm;
        out[o + 64] = mm;
      }
    }
  }
}

extern "C" void kernel_launch(void* const* d_in, const int* in_sizes, int n_in,
                              void* d_out, int out_size, void* d_ws, size_t ws_size,
                              hipStream_t stream) {
  const float* hidden = (const float*)d_in[0];
  const float* W1 = (const float*)d_in[1];
  const float* b1 = (const float*)d_in[2];
  const float* gamma = (const float*)d_in[3];
  const float* beta = (const float*)d_in[4];
  const float* W2 = (const float*)d_in[5];
  const float* b2 = (const float*)d_in[6];
  (void)in_sizes; (void)n_in; (void)out_size; (void)ws_size;

  unsigned short* wp1 = (unsigned short*)d_ws;          // 49152 ushorts
  unsigned short* wp2 = wp1 + 3 * 8 * 4 * 64 * 8;       // 24576 ushorts
  float* gbt = (float*)(wp2 + 3 * 4 * 4 * 64 * 8);      // 864 f32 (padded)
  float* out = (float*)d_out;

  repack_w<<<38, 256, 0, stream>>>(W1, W2, gamma, beta, wp1, wp2, gbt);
  fused_mlp<<<NB, 256, 0, stream>>>(hidden, b1, b2, wp1, wp2, gbt, out);
}

// Round 8
// 142.010 us; speedup vs baseline: 1.8145x; 1.0154x over previous
//
#include <hip/hip_runtime.h>

#define NB 8192
#define NL 64
#define NH 128

typedef __bf16 bf16x8 __attribute__((ext_vector_type(8)));
typedef float f32x4 __attribute__((ext_vector_type(4)));
typedef float f32x2 __attribute__((ext_vector_type(2)));
typedef unsigned short ushort8 __attribute__((ext_vector_type(8)));

// phys->logical permutation for the h buffer (GEMM1 writeback pair-packing):
// phys p = w*32 + ci*2 + half  holds logical  w*32 + half*16 + ci
__device__ __host__ __forceinline__ int p2l(int p) {
  return (p & ~31) + ((p & 1) << 4) + ((p & 31) >> 1);
}
// phys->logical permutation for the x=concat(x1,x2) buffer (x1x2 pair-packing):
// phys even p -> x1 col p/2 ; phys odd p -> x2 col p/2 (logical 64+p/2)
__device__ __host__ __forceinline__ int pi2(int p) {
  return (p & 1) ? 64 + (p >> 1) : (p >> 1);
}

__device__ __forceinline__ unsigned pk2(float lo, float hi) {
  union { __bf16 b[2]; unsigned u; } t;
  t.b[0] = (__bf16)lo; t.b[1] = (__bf16)hi;
  return t.u;
}

// ---------------------------------------------------------------------------
// Repack weights (f32 -> bf16 MFMA-B fragments) + permuted f32 gamma/beta.
// wp1: [layer3][ntile8][kstep4][lane64][reg8]; value = W1[l][srck][n]
//      srck = k (layer 0) | pi2(k) (layers 1,2)   [x-buffer phys layout]
// wp2: [layer3][ntile4][kstep4][lane64][reg8]; value = W2[l][p2l(k)][n]
// gbt: f32 [layer3][2][4(q)][36]; gbt[l][g][q][k] = param[l][p2l(q*32+k)]
// ---------------------------------------------------------------------------
__global__ __launch_bounds__(256) void repack_w(const float* __restrict__ W1,
                                                const float* __restrict__ W2,
                                                const float* __restrict__ gamma,
                                                const float* __restrict__ beta,
                                                unsigned short* __restrict__ wp1,
                                                unsigned short* __restrict__ wp2,
                                                float* __restrict__ gbt) {
  int t = blockIdx.x * 256 + threadIdx.x;
  int lane = t & 63, g = t >> 6;
  if (g < 96) {                                   // W1: 3*8*4 groups
    int layer = g >> 5, rem = g & 31, nt = rem >> 2, ks = rem & 3;
    int n = nt * 16 + (lane & 15);
    int kb = ks * 32 + (lane >> 4) * 8;
    ushort8 v;
#pragma unroll
    for (int r = 0; r < 8; ++r) {
      int k = kb + r;
      int srck = (layer == 0) ? k : pi2(k);
      union { __bf16 b; unsigned short u; } c;
      c.b = (__bf16)W1[(layer * 128 + srck) * 128 + n];
      v[r] = c.u;
    }
    *reinterpret_cast<ushort8*>(wp1 + ((size_t)g * 64 + lane) * 8) = v;
  } else if (g < 144) {                           // W2: 3*4*4 groups, k by p2l
    int g2 = g - 96;
    int layer = g2 >> 4, rem = g2 & 15, nt = rem >> 2, ks = rem & 3;
    int n = nt * 16 + (lane & 15);
    int kb = ks * 32 + (lane >> 4) * 8;
    ushort8 v;
#pragma unroll
    for (int r = 0; r < 8; ++r) {
      union { __bf16 b; unsigned short u; } c;
      c.b = (__bf16)W2[(layer * 128 + p2l(kb + r)) * 64 + n];
      v[r] = c.u;
    }
    *reinterpret_cast<ushort8*>(wp2 + ((size_t)g2 * 64 + lane) * 8) = v;
  } else if (g < 150) {                           // gamma/beta f32, padded
    int g2 = g - 144;                             // 0..5
    int layer = g2 >> 1, param = g2 & 1;
    const float* src = (param == 0 ? gamma : beta) + layer * 128;
    float* dst = gbt + layer * 288 + param * 144;
    int p0 = lane * 2;
#pragma unroll
    for (int u = 0; u < 2; ++u) {
      int p = p0 + u;
      dst[(p >> 5) * 36 + (p & 31)] = src[p2l(p)];
    }
  }
}

// ---------------------------------------------------------------------------
// Fused depth-3 MLP stack, one workgroup (4 waves) per batch row b.
// TWO LDS activation buffers, both bf16 [64][128], 4-bit XOR swizzle
//   byte ^= ((row & 15) << 4)
// xA = x (concat/stage0), xB = h / normalized-h. Dedicated roles kill the
// read-before-overwrite barriers: 3 barriers/layer instead of 5.
// 4-bit swizzle: A-frag ds_read_b128 drops 8-way -> 4-way bank conflict
// (3-bit row XOR aliased with the lg*16 column bits; bit 7 is bank-free).
// NOTE: no min-waves bound — R4/R6 proved forcing 8 waves/EU spills.
// ---------------------------------------------------------------------------
__global__ __launch_bounds__(256) void fused_mlp(
    const float* __restrict__ hidden,
    const float* __restrict__ b1,
    const float* __restrict__ b2,
    const unsigned short* __restrict__ wp1u,
    const unsigned short* __restrict__ wp2u,
    const float* __restrict__ gbt,
    float* __restrict__ out) {
  __shared__ __align__(16) unsigned short xAu[NL * NH];    // 16384 B (x)
  __shared__ __align__(16) unsigned short xBu[NL * NH];    // 16384 B (h/xn)
  __shared__ __align__(16) float gbuf[864];                // 3456 B

  const int tid = threadIdx.x;
  const int wave = tid >> 6, lane = tid & 63;
  const int ci = lane & 15, lg = lane >> 4;
  char* xA = reinterpret_cast<char*>(xAu);
  char* xB = reinterpret_cast<char*>(xBu);

  // thread-invariant address pieces for fragment reads
  const int abase = ci * 256;                 // row (=..+ci) byte base (mod tiles)
  const int axor = ci << 4;                   // 4-bit row swizzle for rows ≡ ci

  // stage gamma/beta (f32, padded layout) into LDS
  if (tid < 96) {
#pragma unroll
    for (int u = 0; u < 9; ++u) gbuf[tid * 9 + u] = gbt[tid * 9 + u];
  }

  // ---- stage 0: load hidden[b] (f32) -> xA (bf16, swizzled, identity) ----
  const float* src = hidden + (size_t)blockIdx.x * (NL * NH);
#pragma unroll
  for (int i = 0; i < 4; ++i) {
    int f = i * 256 + tid;          // 8-elem chunk id, 0..1023
    int row = f >> 4;
    int cb = (f & 15) * 16;         // byte column
    const float4* p = reinterpret_cast<const float4*>(src + f * 8);
    float4 a = p[0], bq = p[1];
    bf16x8 v;
    v[0] = (__bf16)a.x;  v[1] = (__bf16)a.y;  v[2] = (__bf16)a.z;  v[3] = (__bf16)a.w;
    v[4] = (__bf16)bq.x; v[5] = (__bf16)bq.y; v[6] = (__bf16)bq.z; v[7] = (__bf16)bq.w;
    *reinterpret_cast<bf16x8*>(xA + row * 256 + (cb ^ ((row & 15) << 4))) = v;
  }
  __syncthreads();

  for (int layer = 0; layer < 3; ++layer) {
    const unsigned short* wl1 = wp1u + (size_t)layer * 16384;
    const float bv0 = b1[layer * 128 + wave * 32 + ci];
    const float bv1 = b1[layer * 128 + wave * 32 + 16 + ci];
    const int dby = (wave * 16 + ci) * 4;

    // ========== GEMM1: h = x @ W1 + b1 (bias in C-init; wave -> 32 cols) ====
    f32x4 acc[4][2];
#pragma unroll
    for (int mt = 0; mt < 4; ++mt) {
      acc[mt][0] = f32x4{bv0, bv0, bv0, bv0};
      acc[mt][1] = f32x4{bv1, bv1, bv1, bv1};
    }
#pragma unroll
    for (int ks = 0; ks < 4; ++ks) {
      bf16x8 bf0 = *reinterpret_cast<const bf16x8*>(
          wl1 + (((wave * 2 + 0) * 4 + ks) * 64 + lane) * 8);
      bf16x8 bf1 = *reinterpret_cast<const bf16x8*>(
          wl1 + (((wave * 2 + 1) * 4 + ks) * 64 + lane) * 8);
      int cbx = ((ks * 64 + lg * 16) ^ axor) + abase;
#pragma unroll
      for (int mt = 0; mt < 4; ++mt) {
        bf16x8 af = *reinterpret_cast<const bf16x8*>(xA + mt * 4096 + cbx);
        acc[mt][0] = __builtin_amdgcn_mfma_f32_16x16x32_bf16(af, bf0, acc[mt][0], 0, 0, 0);
        acc[mt][1] = __builtin_amdgcn_mfma_f32_16x16x32_bf16(af, bf1, acc[mt][1], 0, 0, 0);
      }
    }
    // writeback h -> xB (no barrier needed: xB has no pending readers)
    // row&15 = lg*4+r, so the swizzle is compile-time per (lg,r)
#pragma unroll
    for (int mt = 0; mt < 4; ++mt)
#pragma unroll
      for (int r = 0; r < 4; ++r) {
        int row = mt * 16 + lg * 4 + r;
        *reinterpret_cast<unsigned*>(
            xB + row * 256 + (dby ^ ((lg * 4 + r) << 4))) =
            pk2(acc[mt][0][r], acc[mt][1][r]);
      }
    __syncthreads();  // β1: h visible to LN

    // prefetch W2 fragments + b2 so L2 latency hides under LN
    const unsigned short* wl2 = wp2u + (size_t)layer * 8192;
    bf16x8 w2f[4];
#pragma unroll
    for (int ks = 0; ks < 4; ++ks)
      w2f[ks] = *reinterpret_cast<const bf16x8*>(
          wl2 + ((wave * 4 + ks) * 64 + lane) * 8);
    float b2v = b2[layer * 64 + wave * 16 + ci];

    // ========== LayerNorm + ReLU on xB in place: 4 threads per row ==========
    {
      const int row = wave * 16 + (lane >> 2);
      const int q = lane & 3;
      const int rb = row * 256, rx = (lane >> 2) << 4;
      bf16x8 h0 = *reinterpret_cast<const bf16x8*>(xB + rb + ((q * 64 + 0) ^ rx));
      bf16x8 h1 = *reinterpret_cast<const bf16x8*>(xB + rb + ((q * 64 + 16) ^ rx));
      bf16x8 h2 = *reinterpret_cast<const bf16x8*>(xB + rb + ((q * 64 + 32) ^ rx));
      bf16x8 h3 = *reinterpret_cast<const bf16x8*>(xB + rb + ((q * 64 + 48) ^ rx));
      f32x2 f[16];
#pragma unroll
      for (int cch = 0; cch < 4; ++cch) {
        bf16x8 hv = (cch == 0) ? h0 : (cch == 1) ? h1 : (cch == 2) ? h2 : h3;
#pragma unroll
        for (int j2 = 0; j2 < 4; ++j2)
          f[cch * 4 + j2] = f32x2{(float)hv[j2 * 2], (float)hv[j2 * 2 + 1]};
      }
      f32x2 s2 = {0.f, 0.f}, q2 = {0.f, 0.f};
#pragma unroll
      for (int i = 0; i < 16; ++i) { s2 += f[i]; q2 += f[i] * f[i]; }
      float s = s2.x + s2.y, sq = q2.x + q2.y;
      s += __shfl_xor(s, 1);  sq += __shfl_xor(sq, 1);
      s += __shfl_xor(s, 2);  sq += __shfl_xor(sq, 2);
      float mu = s * (1.f / 128.f);
      float var = sq * (1.f / 128.f) - mu * mu;
      float rs = rsqrtf(var + 1e-5f);
      const f32x2* gl = reinterpret_cast<const f32x2*>(gbuf + layer * 288 + q * 36);
      const f32x2* bl = reinterpret_cast<const f32x2*>(gbuf + layer * 288 + 144 + q * 36);
#pragma unroll
      for (int cch = 0; cch < 4; ++cch) {
        union { unsigned u[4]; bf16x8 v; } yy;
#pragma unroll
        for (int j2 = 0; j2 < 4; ++j2) {
          int i = cch * 4 + j2;
          f32x2 a2 = gl[i] * rs;
          f32x2 c2 = bl[i] - a2 * mu;
          f32x2 y2 = f[i] * a2 + c2;
          yy.u[j2] = pk2(fmaxf(y2.x, 0.f), fmaxf(y2.y, 0.f));
        }
        *reinterpret_cast<bf16x8*>(xB + rb + ((q * 64 + cch * 16) ^ rx)) = yy.v;
      }
    }
    __syncthreads();  // β2: normalized x visible

    // ========== GEMM2: x1 = xn @ W2 + b2 (bias in C-init; wave -> 16 cols) ==
    f32x4 acc2[4];
#pragma unroll
    for (int mt = 0; mt < 4; ++mt) acc2[mt] = f32x4{b2v, b2v, b2v, b2v};
#pragma unroll
    for (int ks = 0; ks < 4; ++ks) {
      int cbx = ((ks * 64 + lg * 16) ^ axor) + abase;
#pragma unroll
      for (int mt = 0; mt < 4; ++mt) {
        bf16x8 af = *reinterpret_cast<const bf16x8*>(xB + mt * 4096 + cbx);
        acc2[mt] = __builtin_amdgcn_mfma_f32_16x16x32_bf16(af, w2f[ks], acc2[mt], 0, 0, 0);
      }
    }

    // column max over all 64 rows: in-reg + 2 shuffles (lane holds col wave*16+ci)
    float mm;
    {
      float m = -3.0e38f;
#pragma unroll
      for (int mt = 0; mt < 4; ++mt)
#pragma unroll
        for (int r = 0; r < 4; ++r) m = fmaxf(m, acc2[mt][r]);
      m = fmaxf(m, __shfl_xor(m, 16));
      m = fmaxf(m, __shfl_xor(m, 32));
      mm = m;
    }

    if (layer < 2) {
      // pack (x1[row][c], x2[c]) -> xA phys dword d = wave*16+ci
      // (xA's readers all finished before β1; no extra barrier needed)
#pragma unroll
      for (int mt = 0; mt < 4; ++mt)
#pragma unroll
        for (int r = 0; r < 4; ++r) {
          int row = mt * 16 + lg * 4 + r;
          *reinterpret_cast<unsigned*>(
              xA + row * 256 + (dby ^ ((lg * 4 + r) << 4))) =
              pk2(acc2[mt][r], mm);
        }
      __syncthreads();  // β3: new x visible for next layer
    } else {
      // final output (f32): out[b] = [x2_3, x2_3]
      if (lg == 0) {
        size_t o = (size_t)blockIdx.x * 128 + wave * 16 + ci;
        out[o] = mm;
        out[o + 64] = mm;
      }
    }
  }
}

extern "C" void kernel_launch(void* const* d_in, const int* in_sizes, int n_in,
                              void* d_out, int out_size, void* d_ws, size_t ws_size,
                              hipStream_t stream) {
  const float* hidden = (const float*)d_in[0];
  const float* W1 = (const float*)d_in[1];
  const float* b1 = (const float*)d_in[2];
  const float* gamma = (const float*)d_in[3];
  const float* beta = (const float*)d_in[4];
  const float* W2 = (const float*)d_in[5];
  const float* b2 = (const float*)d_in[6];
  (void)in_sizes; (void)n_in; (void)out_size; (void)ws_size;

  unsigned short* wp1 = (unsigned short*)d_ws;          // 49152 ushorts
  unsigned short* wp2 = wp1 + 3 * 8 * 4 * 64 * 8;       // 24576 ushorts
  float* gbt = (float*)(wp2 + 3 * 4 * 4 * 64 * 8);      // 864 f32 (padded)
  float* out = (float*)d_out;

  repack_w<<<38, 256, 0, stream>>>(W1, W2, gamma, beta, wp1, wp2, gbt);
  fused_mlp<<<NB, 256, 0, stream>>>(hidden, b1, b2, wp1, wp2, gbt, out);
}